// Round 12
// baseline (608.733 us; speedup 1.0000x reference)
//
#include <hip/hip_runtime.h>
#include <hip/hip_bf16.h>
#include <math.h>

#define D 256
#define NH 8
#define DH 32
#define LYR 2
#define G 64
#define KK 4096
#define T 4
#define EC 32
#define B 4
#define N 512
#define CITY 256
#define DFF 1024
#define NS 513    // N + 1 bs token
#define NSP 544   // 17 * 32 padded token count
#define MSRC 2052 // B * NS
#define MSRCP 2176 // padded to 34*64
#define ISQ 0.17677669529663687f
#define LOG2E 1.4426950408889634f

typedef short bf16x8 __attribute__((ext_vector_type(8)));
typedef float f32x4 __attribute__((ext_vector_type(4)));

__device__ __forceinline__ float gelu_f(float x) {
    const float c = 0.7978845608028654f;
    float x3 = x * x * x;
    return 0.5f * x * (1.f + tanhf(c * (x + 0.044715f * x3)));
}

__device__ __forceinline__ unsigned short f2bf(float f) {
    unsigned int u = __float_as_uint(f);
    unsigned int r = (u + 0x7FFFu + ((u >> 16) & 1u)) >> 16;
    return (unsigned short)r;
}

__device__ __forceinline__ float bf2f(unsigned short u) {
    return __uint_as_float((unsigned)u << 16);
}

__device__ __forceinline__ unsigned cvtpk(float a, float b) {
    unsigned r;
    asm("v_cvt_pk_bf16_f32 %0, %1, %2" : "=v"(r) : "v"(a), "v"(b));
    return r;
}

__device__ __forceinline__ void gl2lds16(const unsigned short* g, unsigned short* l) {
    __builtin_amdgcn_global_load_lds(
        (const __attribute__((address_space(1))) unsigned int*)g,
        (__attribute__((address_space(3))) unsigned int*)l, 16, 0, 0);
}

// ================= pre1: transposes + tok_mlp + density + conv1 + tvec + K/V pad zero ===========
__global__ __launch_bounds__(256) void pre1_k(
    const float* __restrict__ wq, const float* __restrict__ wk,
    const float* __restrict__ wv, const float* __restrict__ wo,
    const float* __restrict__ ff1, const float* __restrict__ ff2,
    const float* __restrict__ tfp,
    const float* __restrict__ bk, const float* __restrict__ bv,
    unsigned short* __restrict__ wqT, unsigned short* __restrict__ kvT,
    unsigned short* __restrict__ woT, unsigned short* __restrict__ ff1T,
    unsigned short* __restrict__ ff2T, unsigned short* __restrict__ tfpT,
    float* __restrict__ kvbias,
    const float* __restrict__ meas_xy, const float* __restrict__ meas_v,
    const float* __restrict__ bs_xy,
    const float* __restrict__ mp_w1, const float* __restrict__ mp_b1,
    const float* __restrict__ mp_w2, const float* __restrict__ mp_b2,
    const float* __restrict__ bp_w1, const float* __restrict__ bp_b1,
    const float* __restrict__ bp_w2, const float* __restrict__ bp_b2,
    unsigned short* __restrict__ srcbf, float* __restrict__ src_xy,
    float* __restrict__ dens,
    const float* __restrict__ city, const float* __restrict__ env_w1,
    const float* __restrict__ env_b1, float* __restrict__ h1,
    const float* __restrict__ task_emb, const int* __restrict__ task_id,
    const float* __restrict__ tp_w, const float* __restrict__ tp_b,
    float* __restrict__ tvec,
    unsigned short* __restrict__ khd, unsigned short* __restrict__ vch)
{
    __shared__ float sh[1088];
    int bx = blockIdx.x;
    int tid = threadIdx.x;
    if (bx < 1792) {
        const float* src; unsigned short* dst;
        int Kd, Nn, nmat, rowOff = 0, t; size_t matStride;
        if (bx < 512) {
            int job = bx >> 7; t = bx & 127;
            Kd = 256; Nn = 256; nmat = 2;
            if (job == 0)      { src = wq; dst = wqT; matStride = 65536; }
            else if (job == 1) { src = wk; dst = kvT; matStride = 131072; }
            else if (job == 2) { src = wv; dst = kvT; matStride = 131072; rowOff = 256; }
            else               { src = wo; dst = woT; matStride = 65536; }
            if ((t & 63) == 0 && job == 1) kvbias[(t >> 6) * 512 + tid] = bk[(t >> 6) * 256 + tid];
            if ((t & 63) == 0 && job == 2) kvbias[(t >> 6) * 512 + 256 + tid] = bv[(t >> 6) * 256 + tid];
        } else if (bx < 1024) { t = bx - 512;  src = ff1; dst = ff1T; Kd = 256;  Nn = 1024; nmat = 2; matStride = 262144; }
        else if (bx < 1536)   { t = bx - 1024; src = ff2; dst = ff2T; Kd = 1024; Nn = 256;  nmat = 2; matStride = 262144; }
        else                  { t = bx - 1536; src = tfp; dst = tfpT; Kd = 256;  Nn = 256;  nmat = 4; matStride = 65536; }
        int tn = Nn / 32, perMat = tn * (Kd / 32);
        int mat = t / perMat;
        int rem = t - mat * perMat;
        int nb = (rem % tn) * 32, kb = (rem / tn) * 32;
        const float* s = src + (size_t)mat * Kd * Nn;
        unsigned short* d = dst + (size_t)mat * matStride;
        float (*tb)[33] = (float (*)[33])sh;
        int tx = tid & 31, ty = tid >> 5;
        #pragma unroll
        for (int i = 0; i < 4; i++)
            tb[ty + i * 8][tx] = s[(size_t)(kb + ty + i * 8) * Nn + nb + tx];
        __syncthreads();
        #pragma unroll
        for (int i = 0; i < 4; i++)
            d[(size_t)(rowOff + nb + ty + i * 8) * Kd + kb + tx] = f2bf(tb[tx][ty + i * 8]);
    } else if (bx < 3968) {
        int id = bx - 1792;
        int dd = tid;
        if (id >= B * N + B) {
            srcbf[(size_t)id * D + dd] = 0;
            return;
        }
        float* hid = sh;
        int row;
        const float *w1, *b1, *w2, *b2;
        float x0, x1, x2 = 0.f;
        int nin;
        if (id < B * N) {
            int b = id >> 9, n = id & 511;
            x0 = meas_xy[(b * N + n) * 2 + 0];
            x1 = meas_xy[(b * N + n) * 2 + 1];
            x2 = meas_v[b * N + n];
            w1 = mp_w1; b1 = mp_b1; w2 = mp_w2; b2 = mp_b2; nin = 3;
            row = b * NS + n;
        } else {
            int b = id - B * N;
            x0 = bs_xy[b * 2 + 0];
            x1 = bs_xy[b * 2 + 1];
            w1 = bp_w1; b1 = bp_b1; w2 = bp_w2; b2 = bp_b2; nin = 2;
            row = b * NS + N;
        }
        float h = x0 * w1[dd] + x1 * w1[D + dd] + b1[dd];
        if (nin == 3) h += x2 * w1[2 * D + dd];
        hid[dd] = gelu_f(h);
        __syncthreads();
        float o = b2[dd];
        for (int j = 0; j < D; j++) o += hid[j] * w2[j * D + dd];
        srcbf[(size_t)row * D + dd] = f2bf(o);
        if (dd == 0) { src_xy[row * 2 + 0] = x0; src_xy[row * 2 + 1] = x1; }
    } else if (bx < 4032) {
        int blk = bx - 3968;
        int b = blk >> 4, kc = blk & 15;
        int k = kc * 256 + tid;
        float* mx = sh; float* my = sh + 512;
        for (int i = tid; i < N; i += 256) {
            mx[i] = meas_xy[(b * N + i) * 2 + 0];
            my[i] = meas_xy[(b * N + i) * 2 + 1];
        }
        __syncthreads();
        float gx = ((k & 63) + 0.5f) / 64.f;
        float gy = ((k >> 6) + 0.5f) / 64.f;
        float s = 0.f;
        for (int n = 0; n < N; n++) {
            float dx = gx - mx[n], dy = gy - my[n];
            s += __expf(-(dx * dx + dy * dy) * 78.125f);
        }
        dens[b * KK + k] = s * (1.f / (float)N);
    } else if (bx < 6080) {
        int i = (bx - 4032) * 256 + tid;
        int x = i & 63, y = (i >> 6) & 63, c = (i >> 12) & 31, b = i >> 17;
        float s = env_b1[c];
        for (int ky = 0; ky < 3; ky++) {
            int yy = y + ky - 1;
            if (yy < 0 || yy >= G) continue;
            for (int kx = 0; kx < 3; kx++) {
                int xx = x + kx - 1;
                if (xx < 0 || xx >= G) continue;
                s += city[(b * CITY + yy * 4) * CITY + xx * 4] * env_w1[c * 9 + ky * 3 + kx];
            }
        }
        h1[i] = gelu_f(s);
    } else if (bx < 6084) {
        int b = bx - 6080;
        float* e = sh;
        e[tid] = task_emb[task_id[b] * D + tid];
        __syncthreads();
        float s = tp_b[tid];
        for (int j = 0; j < D; j++) s += e[j] * tp_w[j * D + tid];
        tvec[b * D + tid] = s;
    } else {
        int bh = bx - 6084;     // 0..31
        unsigned short* kp = khd + ((size_t)bh * 544 + 513) * 32;
        for (int i = tid; i < 992; i += 256) kp[i] = 0;
        unsigned short* vp = vch + ((size_t)bh * 17 + 16) * 1024;
        for (int i = tid; i < 1024; i += 256) vp[i] = 0;
    }
}

// ================= conv2: branchless, 4 c_out/thread, ci-pipelined =================
__global__ __launch_bounds__(256) void conv2_k(
    const float* __restrict__ h1, const float* __restrict__ w,
    const float* __restrict__ bias, float* __restrict__ h2) {
    int blk = blockIdx.x;
    int yt = blk & 15, cg = (blk >> 4) & 7, b = blk >> 7;
    int x = threadIdx.x & 63, y = yt * 4 + (threadIdx.x >> 6);
    int c0 = cg * 4;
    float flag[9];
    int off[9];
    #pragma unroll
    for (int ky = 0; ky < 3; ky++) {
        int yy = y + ky - 1;
        bool vy = (yy >= 0 && yy < G);
        int yc = min(max(yy, 0), G - 1);
        #pragma unroll
        for (int kx = 0; kx < 3; kx++) {
            int xx = x + kx - 1;
            bool vx = (xx >= 0 && xx < G);
            int xc = min(max(xx, 0), G - 1);
            flag[ky * 3 + kx] = (vy && vx) ? 1.f : 0.f;
            off[ky * 3 + kx] = yc * G + xc;
        }
    }
    const float* hp = h1 + ((size_t)(b * EC) << 12);
    float acc[4] = {bias[c0], bias[c0 + 1], bias[c0 + 2], bias[c0 + 3]};
    float v[9], nv[9];
    #pragma unroll
    for (int t = 0; t < 9; t++) v[t] = hp[off[t]] * flag[t];
    for (int ci = 0; ci < EC; ci++) {
        if (ci < EC - 1) {
            const float* hn = hp + ((size_t)(ci + 1) << 12);
            #pragma unroll
            for (int t = 0; t < 9; t++) nv[t] = hn[off[t]] * flag[t];
        }
        #pragma unroll
        for (int cc = 0; cc < 4; cc++) {
            const float* wp = w + ((size_t)(c0 + cc) * EC + ci) * 9;
            #pragma unroll
            for (int t = 0; t < 9; t++) acc[cc] += v[t] * wp[t];
        }
        #pragma unroll
        for (int t = 0; t < 9; t++) v[t] = nv[t];
    }
    size_t obase = (((size_t)(b * EC + c0)) << 12) + y * G + x;
    #pragma unroll
    for (int cc = 0; cc < 4; cc++)
        h2[obase + ((size_t)cc << 12)] = gelu_f(acc[cc]);
}

// ================= pre2: grid_init + swizzled nd (pre-scaled by log2e) + out_init =================
// ndL layout: [b][qt64][c17][half2][q4(4)][query16x4(64)][r4] ushort
__global__ __launch_bounds__(256) void pre2_k(
    const float* __restrict__ h2, const float* __restrict__ w3,
    const float* __restrict__ b3, const float* __restrict__ grid_pos,
    const float* __restrict__ tvec, float* __restrict__ grid,
    const float* __restrict__ sxy, unsigned short* __restrict__ nd,
    float* __restrict__ out, const float* __restrict__ head_b)
{
    __shared__ float sh[1088];
    int bx = blockIdx.x;
    int tid = threadIdx.x;
    if (bx < 2048) {
        int b = bx >> 9, k0 = (bx & 511) * 8;
        float (*h2s)[8] = (float (*)[8])sh;
        h2s[tid >> 3][tid & 7] = h2[(((size_t)b * EC + (tid >> 3)) << 12) + k0 + (tid & 7)];
        float w3r[32];
        #pragma unroll
        for (int c4 = 0; c4 < 8; c4++) {
            float4 w4 = *(const float4*)(w3 + tid * 32 + c4 * 4);
            w3r[c4 * 4 + 0] = w4.x; w3r[c4 * 4 + 1] = w4.y;
            w3r[c4 * 4 + 2] = w4.z; w3r[c4 * 4 + 3] = w4.w;
        }
        float base = b3[tid] + tvec[b * D + tid];
        __syncthreads();
        #pragma unroll
        for (int j = 0; j < 8; j++) {
            float s = base + grid_pos[(size_t)(k0 + j) * D + tid];
            #pragma unroll
            for (int ci = 0; ci < 32; ci++) s += h2s[ci][j] * w3r[ci];
            grid[((size_t)b * KK + k0 + j) * D + tid] = s;
        }
    } else if (bx < 2304) {
        int q = bx - 2048;          // b*64 + qt
        int b = q >> 6, qt = q & 63;
        float* sxs = sh; float* sys = sh + 544;
        for (int i = tid; i < 544; i += 256) {
            float x = 0.f, y = 0.f;
            if (i < NS) { x = sxy[(b * NS + i) * 2]; y = sxy[(b * NS + i) * 2 + 1]; }
            sxs[i] = x; sys[i] = y;
        }
        __syncthreads();
        unsigned short* base = nd + (size_t)q * 34816;
        for (int c = 0; c < 17; c++) {
            #pragma unroll
            for (int it = 0; it < 2; it++) {
                int lin = it * 256 + tid;
                int w16 = lin & 63, q4 = (lin >> 6) & 3, half = lin >> 8;
                int qidx = qt * 64 + w16;
                float gx = ((qidx & 63) + 0.5f) * (1.f / 64.f);
                float gy = ((qidx >> 6) + 0.5f) * (1.f / 64.f);
                unsigned short vs[4];
                #pragma unroll
                for (int r = 0; r < 4; r++) {
                    int tok = c * 32 + half * 16 + q4 * 4 + r;
                    float val;
                    if (tok < NS) {
                        float dx = gx - sxs[tok], dy = gy - sys[tok];
                        val = -sqrtf(dx * dx + dy * dy);
                    } else val = -1e4f;
                    vs[r] = f2bf(val * LOG2E);   // pre-scaled for exp2
                }
                ushort4 o; o.x = vs[0]; o.y = vs[1]; o.z = vs[2]; o.w = vs[3];
                *(ushort4*)(base + (size_t)c * 2048 + lin * 4) = o;
            }
        }
    } else {
        out[(bx - 2304) * 256 + tid] = head_b[0];
    }
}

// ================= fused density-inject + layernorm -> bf16 =================
template <int DENS>
__global__ __launch_bounds__(256) void dens_ln_k(
    float* __restrict__ grid, const float* __restrict__ dens,
    const float* __restrict__ dw, const float* __restrict__ db,
    const float* __restrict__ lw, const float* __restrict__ lb,
    unsigned short* __restrict__ y) {
    int row = blockIdx.x * 4 + (threadIdx.x >> 6);
    int lane = threadIdx.x & 63;
    float* gp = grid + (size_t)row * D + lane * 4;
    float4 v = *(float4*)gp;
    if (DENS) {
        float de = dens[row];
        float4 w4 = *(const float4*)(dw + lane * 4);
        float4 b4 = *(const float4*)(db + lane * 4);
        v.x += de * w4.x + b4.x; v.y += de * w4.y + b4.y;
        v.z += de * w4.z + b4.z; v.w += de * w4.w + b4.w;
        *(float4*)gp = v;
    }
    float s = v.x + v.y + v.z + v.w;
    #pragma unroll
    for (int o = 32; o > 0; o >>= 1) s += __shfl_xor(s, o);
    float mean = s * (1.f / D);
    float cx = v.x - mean, cy = v.y - mean, cz = v.z - mean, cw = v.w - mean;
    float q = cx * cx + cy * cy + cz * cz + cw * cw;
    #pragma unroll
    for (int o = 32; o > 0; o >>= 1) q += __shfl_xor(q, o);
    float inv = rsqrtf(q * (1.f / D) + 1e-5f);
    float4 lwv = *(const float4*)(lw + lane * 4);
    float4 lbv = *(const float4*)(lb + lane * 4);
    ushort4 o4;
    o4.x = f2bf(cx * inv * lwv.x + lbv.x);
    o4.y = f2bf(cy * inv * lwv.y + lbv.y);
    o4.z = f2bf(cz * inv * lwv.z + lbv.z);
    o4.w = f2bf(cw * inv * lwv.w + lbv.w);
    *(ushort4*)(y + (size_t)row * D + lane * 4) = o4;
}

// ================= GEMM core: C[M,N] = A[M,K] @ Wt[N,K]^T + bias =================
// BM=64, BN=64, BK=64, double-buffered LDS.
template <int GELU, int ACCUM, int OBF, int TFPH, int STBF, int KVT = 0>
__device__ __forceinline__ void gemm_core(
    const unsigned short* __restrict__ A, const unsigned short* __restrict__ Wt,
    const float* __restrict__ bias, void* __restrict__ Cv,
    int M, int K, int Nn, int bn, int bm,
    const float* __restrict__ hw, unsigned short* __restrict__ Xb, float scale,
    unsigned short* As, unsigned short* Bs) {
    int tid = threadIdx.x;
    int wave = tid >> 6, lane = tid & 63;
    int q4 = lane >> 4, lr = lane & 15;
    int wn = wave * 16;
    int srow = tid >> 2, sk8 = (tid & 3) * 8;
    const unsigned short* Ap  = A  + (size_t)(bm + srow) * K + sk8;
    const unsigned short* Bp0 = Wt + (size_t)(bn + srow) * K + sk8;
    unsigned short* AsD = As + tid * 8;
    unsigned short* BsD = Bs + tid * 8;
    f32x4 acc[4] = {};

    gl2lds16(Ap,       AsD);
    gl2lds16(Ap + 32,  AsD + 2048);
    gl2lds16(Bp0,      BsD);
    gl2lds16(Bp0 + 32, BsD + 2048);

    int nk = K >> 6;
    for (int ki = 0; ki < nk; ki++) {
        __syncthreads();
        if (ki + 1 < nk) {
            int k0 = (ki + 1) << 6;
            int nb = ((ki + 1) & 1) * 4096;
            gl2lds16(Ap + k0,       AsD + nb);
            gl2lds16(Ap + k0 + 32,  AsD + nb + 2048);
            gl2lds16(Bp0 + k0,      BsD + nb);
            gl2lds16(Bp0 + k0 + 32, BsD + nb + 2048);
        }
        int cb = (ki & 1) * 4096;
        #pragma unroll
        for (int ks = 0; ks < 2; ks++) {
            bf16x8 af[4], bf;
            #pragma unroll
            for (int i = 0; i < 4; i++)
                af[i] = *(const bf16x8*)&As[cb + ks * 2048 + (i * 16 + lr) * 32 + q4 * 8];
            bf = *(const bf16x8*)&Bs[cb + ks * 2048 + (wn + lr) * 32 + q4 * 8];
            #pragma unroll
            for (int i = 0; i < 4; i++)
                acc[i] = __builtin_amdgcn_mfma_f32_16x16x32_bf16(af[i], bf, acc[i], 0, 0, 0);
        }
    }

    if (KVT) {
        int gc = bn + wn + lr;
        float bv = bias[gc];
        bool isV = gc >= 256;
        #pragma unroll
        for (int i = 0; i < 4; i++) {
            #pragma unroll
            for (int r = 0; r < 4; r++) {
                int gr = bm + i * 16 + q4 * 4 + r;
                if (gr < MSRC) {
                    float v = acc[i][r] + bv;
                    int bb = gr / NS;
                    int tok = gr - bb * NS;
                    if (!isV) {
                        int h = gc >> 5, dh = gc & 31;
                        ((unsigned short*)Cv)[(((size_t)(bb * 8 + h) * 544) + tok) * 32 + dh] = f2bf(v);
                    } else {
                        int gcv = gc - 256;
                        int h = gcv >> 5, dh = gcv & 31;
                        int c = tok >> 5, t32 = tok & 31;
                        Xb[((((size_t)(bb * 8 + h) * 17 + c) * 32 + dh)) * 32 + t32] = f2bf(v);
                    }
                }
            }
        }
        return;
    }

    if (TFPH) {
        int gc = bn + wn + lr;
        float bv = bias[gc];
        float hv = hw[gc];
        #pragma unroll
        for (int i = 0; i < 4; i++) {
            #pragma unroll
            for (int r = 0; r < 4; r++) {
                float s = gelu_f(acc[i][r] + bv) * hv;
                s += __shfl_xor(s, 1); s += __shfl_xor(s, 2);
                s += __shfl_xor(s, 4); s += __shfl_xor(s, 8);
                if (lr == 0)
                    atomicAdd((float*)Cv + (bm + i * 16 + q4 * 4 + r), s);
            }
        }
        return;
    }

    int gc = bn + wn + lr;
    float bv = bias[gc];
    #pragma unroll
    for (int i = 0; i < 4; i++) {
        #pragma unroll
        for (int r = 0; r < 4; r++) {
            int gr = bm + i * 16 + q4 * 4 + r;
            if (gr < M) {
                float v = (acc[i][r] + bv) * scale;
                if (GELU) v = gelu_f(v);
                size_t idx = (size_t)gr * Nn + gc;
                if (OBF) {
                    ((unsigned short*)Cv)[idx] = f2bf(v);
                } else if (ACCUM) {
                    float nv = ((float*)Cv)[idx] + v;
                    ((float*)Cv)[idx] = nv;
                    if (STBF) Xb[idx] = f2bf(nv);
                } else {
                    ((float*)Cv)[idx] = v;
                }
            }
        }
    }
}

template <int GELU, int ACCUM, int OBF, int TFPH, int STBF>
__global__ __launch_bounds__(256) void gemm_k(
    const unsigned short* __restrict__ A, const unsigned short* __restrict__ Wt0,
    const float* __restrict__ bias0, void* __restrict__ Cv,
    int M, int K, int Nn, const int* __restrict__ task_id,
    const float* __restrict__ hw, unsigned short* __restrict__ Xb) {
    __shared__ unsigned short As[8192];
    __shared__ unsigned short Bs[8192];
    const unsigned short* Wt = Wt0;
    const float* bias = bias0;
    int bm = blockIdx.y * 64;
    if (TFPH) { int t = task_id[bm >> 12]; Wt += (size_t)t * D * D; bias += t * D; }
    gemm_core<GELU, ACCUM, OBF, TFPH, STBF>(A, Wt, bias, Cv, M, K, Nn,
                                            blockIdx.x * 64, bm, hw, Xb, 1.f, As, Bs);
}

// fused Q + KV projections. Q scaled by isq*log2e (softmax uses exp2); K -> khd, V -> vch.
__global__ __launch_bounds__(256) void qkv_k(
    const unsigned short* __restrict__ xbf, const unsigned short* __restrict__ wqT,
    const float* __restrict__ bq, unsigned short* __restrict__ qbf,
    const unsigned short* __restrict__ srcbf, const unsigned short* __restrict__ kvT,
    const float* __restrict__ kvb, unsigned short* __restrict__ khd,
    unsigned short* __restrict__ vch) {
    __shared__ unsigned short As[8192];
    __shared__ unsigned short Bs[8192];
    if (blockIdx.x < 4) {
        gemm_core<0, 0, 1, 0, 0, 0>(xbf, wqT, bq, qbf, B * KK, D, D,
                                    blockIdx.x * 64, blockIdx.y * 64, nullptr, nullptr,
                                    ISQ * LOG2E, As, Bs);
    } else {
        if (blockIdx.y >= MSRCP / 64) return;
        gemm_core<0, 0, 1, 0, 0, 1>(srcbf, kvT, kvb, khd, MSRC, D, 512,
                                    (blockIdx.x - 4) * 64, blockIdx.y * 64, nullptr, vch, 1.f, As, Bs);
    }
}

// ================= MFMA flash cross-attention, zero-LDS, dense, unroll-2 =================
// S' = K Q^T (query=col, q pre-scaled isq*log2e), p = exp2(s + nd2); O^T = V^T P'.
// Two independent softmax/PV chains (even/odd chunks) for ILP; chunk 16 epilogue.
__global__ __launch_bounds__(256) void attn_mfma(
    const unsigned short* __restrict__ qb,
    const unsigned short* __restrict__ khd,
    const unsigned short* __restrict__ vch,
    const unsigned short* __restrict__ ndL,
    unsigned short* __restrict__ out)
{
    int bid = blockIdx.x;                    // b*512 + h*64 + qt
    int qt = bid & 63, h = (bid >> 6) & 7, b = bid >> 9;
    int tid = threadIdx.x, wave = tid >> 6, lane = tid & 63;
    int q4 = lane >> 4, lr = lane & 15;

    int kbase = qt * 64 + wave * 16;
    size_t qrow = (size_t)(b * KK + kbase + lr);
    bf16x8 qf = *(const bf16x8*)(qb + qrow * D + h * DH + q4 * 8);
    const unsigned short* kp0 = khd + ((size_t)(b * 8 + h) * 544) * 32 + lr * 32 + q4 * 8;
    const unsigned short* vb0 = vch + ((size_t)(b * 8 + h) * 17) * 1024 + lr * 32 + q4 * 8;
    const unsigned short* ndp = ndL + ((size_t)(b * 64 + qt)) * 34816 + q4 * 256 + (wave * 16 + lr) * 4;

    float llA = 0.f, llB = 0.f;
    f32x4 oA0 = {0.f, 0.f, 0.f, 0.f}, oA1 = {0.f, 0.f, 0.f, 0.f};
    f32x4 oB0 = {0.f, 0.f, 0.f, 0.f}, oB1 = {0.f, 0.f, 0.f, 0.f};
    int sA = ((lane >> 4) & 1) * 32 + lr;
    int sB = sA + 16;
    bool hi = (lane & 32) != 0;

    // prefetch chunks 0 (A-regs) and 1 (B-regs)
    bf16x8 kfa0 = *(const bf16x8*)kp0;
    bf16x8 kfa1 = *(const bf16x8*)(kp0 + 512);
    bf16x8 vta0 = *(const bf16x8*)vb0;
    bf16x8 vta1 = *(const bf16x8*)(vb0 + 512);
    ushort4 na0 = *(const ushort4*)ndp;
    ushort4 na1 = *(const ushort4*)(ndp + 1024);
    bf16x8 kfb0 = *(const bf16x8*)(kp0 + 1024);
    bf16x8 kfb1 = *(const bf16x8*)(kp0 + 1536);
    bf16x8 vtb0 = *(const bf16x8*)(vb0 + 1024);
    bf16x8 vtb1 = *(const bf16x8*)(vb0 + 1536);
    ushort4 nb0 = *(const ushort4*)(ndp + 2048);
    ushort4 nb1 = *(const ushort4*)(ndp + 3072);

    for (int i = 0; i < 8; i++) {
        bf16x8 cka0 = kfa0, cka1 = kfa1, cva0 = vta0, cva1 = vta1;
        ushort4 cna0 = na0, cna1 = na1;
        bf16x8 ckb0 = kfb0, ckb1 = kfb1, cvb0 = vtb0, cvb1 = vtb1;
        ushort4 cnb0 = nb0, cnb1 = nb1;
        if (i < 7) {
            size_t ca = (size_t)(2 * i + 2) * 1024;
            kfa0 = *(const bf16x8*)(kp0 + ca);
            kfa1 = *(const bf16x8*)(kp0 + ca + 512);
            vta0 = *(const bf16x8*)(vb0 + ca);
            vta1 = *(const bf16x8*)(vb0 + ca + 512);
            na0 = *(const ushort4*)(ndp + (size_t)(2 * i + 2) * 2048);
            na1 = *(const ushort4*)(ndp + (size_t)(2 * i + 2) * 2048 + 1024);
            kfb0 = *(const bf16x8*)(kp0 + ca + 1024);
            kfb1 = *(const bf16x8*)(kp0 + ca + 1536);
            vtb0 = *(const bf16x8*)(vb0 + ca + 1024);
            vtb1 = *(const bf16x8*)(vb0 + ca + 1536);
            nb0 = *(const ushort4*)(ndp + (size_t)(2 * i + 3) * 2048);
            nb1 = *(const ushort4*)(ndp + (size_t)(2 * i + 3) * 2048 + 1024);
        } else {
            size_t ca = (size_t)16 * 1024;      // chunk 16 -> A-regs for epilogue
            kfa0 = *(const bf16x8*)(kp0 + ca);
            kfa1 = *(const bf16x8*)(kp0 + ca + 512);
            vta0 = *(const bf16x8*)(vb0 + ca);
            vta1 = *(const bf16x8*)(vb0 + ca + 512);
            na0 = *(const ushort4*)(ndp + (size_t)16 * 2048);
            na1 = *(const ushort4*)(ndp + (size_t)16 * 2048 + 1024);
        }
        // QK for both chunks
        f32x4 sa0 = {0.f, 0.f, 0.f, 0.f}, sa1 = {0.f, 0.f, 0.f, 0.f};
        f32x4 sb0 = {0.f, 0.f, 0.f, 0.f}, sb1 = {0.f, 0.f, 0.f, 0.f};
        sa0 = __builtin_amdgcn_mfma_f32_16x16x32_bf16(cka0, qf, sa0, 0, 0, 0);
        sa1 = __builtin_amdgcn_mfma_f32_16x16x32_bf16(cka1, qf, sa1, 0, 0, 0);
        sb0 = __builtin_amdgcn_mfma_f32_16x16x32_bf16(ckb0, qf, sb0, 0, 0, 0);
        sb1 = __builtin_amdgcn_mfma_f32_16x16x32_bf16(ckb1, qf, sb1, 0, 0, 0);
        // softmax, two independent streams
        float pa0[4], pa1[4], pb0[4], pb1[4];
        pa0[0] = __builtin_amdgcn_exp2f(sa0[0] + bf2f(cna0.x));
        pa0[1] = __builtin_amdgcn_exp2f(sa0[1] + bf2f(cna0.y));
        pa0[2] = __builtin_amdgcn_exp2f(sa0[2] + bf2f(cna0.z));
        pa0[3] = __builtin_amdgcn_exp2f(sa0[3] + bf2f(cna0.w));
        pa1[0] = __builtin_amdgcn_exp2f(sa1[0] + bf2f(cna1.x));
        pa1[1] = __builtin_amdgcn_exp2f(sa1[1] + bf2f(cna1.y));
        pa1[2] = __builtin_amdgcn_exp2f(sa1[2] + bf2f(cna1.z));
        pa1[3] = __builtin_amdgcn_exp2f(sa1[3] + bf2f(cna1.w));
        pb0[0] = __builtin_amdgcn_exp2f(sb0[0] + bf2f(cnb0.x));
        pb0[1] = __builtin_amdgcn_exp2f(sb0[1] + bf2f(cnb0.y));
        pb0[2] = __builtin_amdgcn_exp2f(sb0[2] + bf2f(cnb0.z));
        pb0[3] = __builtin_amdgcn_exp2f(sb0[3] + bf2f(cnb0.w));
        pb1[0] = __builtin_amdgcn_exp2f(sb1[0] + bf2f(cnb1.x));
        pb1[1] = __builtin_amdgcn_exp2f(sb1[1] + bf2f(cnb1.y));
        pb1[2] = __builtin_amdgcn_exp2f(sb1[2] + bf2f(cnb1.z));
        pb1[3] = __builtin_amdgcn_exp2f(sb1[3] + bf2f(cnb1.w));
        llA += ((pa0[0] + pa0[1]) + (pa0[2] + pa0[3])) + ((pa1[0] + pa1[1]) + (pa1[2] + pa1[3]));
        llB += ((pb0[0] + pb0[1]) + (pb0[2] + pb0[3])) + ((pb1[0] + pb1[1]) + (pb1[2] + pb1[3]));
        // transpose + PV, chunk A
        {
            unsigned pk0 = cvtpk(pa0[0], pa0[1]);
            unsigned pk1 = cvtpk(pa0[2], pa0[3]);
            unsigned pk2 = cvtpk(pa1[0], pa1[1]);
            unsigned pk3 = cvtpk(pa1[2], pa1[3]);
            unsigned a0 = (unsigned)__shfl((int)pk0, sA), c0 = (unsigned)__shfl((int)pk2, sA);
            unsigned a1 = (unsigned)__shfl((int)pk1, sA), c1 = (unsigned)__shfl((int)pk3, sA);
            unsigned a2 = (unsigned)__shfl((int)pk0, sB), c2 = (unsigned)__shfl((int)pk2, sB);
            unsigned a3 = (unsigned)__shfl((int)pk1, sB), c3 = (unsigned)__shfl((int)pk3, sB);
            union { unsigned u[4]; bf16x8 v; } pu;
            pu.u[0] = hi ? c0 : a0;
            pu.u[1] = hi ? c1 : a1;
            pu.u[2] = hi ? c2 : a2;
            pu.u[3] = hi ? c3 : a3;
            oA0 = __builtin_amdgcn_mfma_f32_16x16x32_bf16(cva0, pu.v, oA0, 0, 0, 0);
            oA1 = __builtin_amdgcn_mfma_f32_16x16x32_bf16(cva1, pu.v, oA1, 0, 0, 0);
        }
        // transpose + PV, chunk B
        {
            unsigned pk0 = cvtpk(pb0[0], pb0[1]);
            unsigned pk1 = cvtpk(pb0[2], pb0[3]);
            unsigned pk2 = cvtpk(pb1[0], pb1[1]);
            unsigned pk3 = cvtpk(pb1[2], pb1[3]);
            unsigned a0 = (unsigned)__shfl((int)pk0, sA), c0 = (unsigned)__shfl((int)pk2, sA);
            unsigned a1 = (unsigned)__shfl((int)pk1, sA), c1 = (unsigned)__shfl((int)pk3, sA);
            unsigned a2 = (unsigned)__shfl((int)pk0, sB), c2 = (unsigned)__shfl((int)pk2, sB);
            unsigned a3 = (unsigned)__shfl((int)pk1, sB), c3 = (unsigned)__shfl((int)pk3, sB);
            union { unsigned u[4]; bf16x8 v; } pu;
            pu.u[0] = hi ? c0 : a0;
            pu.u[1] = hi ? c1 : a1;
            pu.u[2] = hi ? c2 : a2;
            pu.u[3] = hi ? c3 : a3;
            oB0 = __builtin_amdgcn_mfma_f32_16x16x32_bf16(cvb0, pu.v, oB0, 0, 0, 0);
            oB1 = __builtin_amdgcn_mfma_f32_16x16x32_bf16(cvb1, pu.v, oB1, 0, 0, 0);
        }
    }
    // epilogue: chunk 16 (in A-regs)
    {
        f32x4 s0 = {0.f, 0.f, 0.f, 0.f}, s1 = {0.f, 0.f, 0.f, 0.f};
        s0 = __builtin_amdgcn_mfma_f32_16x16x32_bf16(kfa0, qf, s0, 0, 0, 0);
        s1 = __builtin_amdgcn_mfma_f32_16x16x32_bf16(kfa1, qf, s1, 0, 0, 0);
        float p0[4], p1[4];
        p0[0] = __builtin_amdgcn_exp2f(s0[0] + bf2f(na0.x));
        p0[1] = __builtin_amdgcn_exp2f(s0[1] + bf2f(na0.y));
        p0[2] = __builtin_amdgcn_exp2f(s0[2] + bf2f(na0.z));
        p0[3] = __builtin_amdgcn_exp2f(s0[3] + bf2f(na0.w));
        p1[0] = __builtin_amdgcn_exp2f(s1[0] + bf2f(na1.x));
        p1[1] = __builtin_amdgcn_exp2f(s1[1] + bf2f(na1.y));
        p1[2] = __builtin_amdgcn_exp2f(s1[2] + bf2f(na1.z));
        p1[3] = __builtin_amdgcn_exp2f(s1[3] + bf2f(na1.w));
        llA += ((p0[0] + p0[1]) + (p0[2] + p0[3])) + ((p1[0] + p1[1]) + (p1[2] + p1[3]));
        unsigned pk0 = cvtpk(p0[0], p0[1]);
        unsigned pk1 = cvtpk(p0[2], p0[3]);
        unsigned pk2 = cvtpk(p1[0], p1[1]);
        unsigned pk3 = cvtpk(p1[2], p1[3]);
        unsigned a0 = (unsigned)__shfl((int)pk0, sA), c0 = (unsigned)__shfl((int)pk2, sA);
        unsigned a1 = (unsigned)__shfl((int)pk1, sA), c1 = (unsigned)__shfl((int)pk3, sA);
        unsigned a2 = (unsigned)__shfl((int)pk0, sB), c2 = (unsigned)__shfl((int)pk2, sB);
        unsigned a3 = (unsigned)__shfl((int)pk1, sB), c3 = (unsigned)__shfl((int)pk3, sB);
        union { unsigned u[4]; bf16x8 v; } pu;
        pu.u[0] = hi ? c0 : a0;
        pu.u[1] = hi ? c1 : a1;
        pu.u[2] = hi ? c2 : a2;
        pu.u[3] = hi ? c3 : a3;
        oA0 = __builtin_amdgcn_mfma_f32_16x16x32_bf16(vta0, pu.v, oA0, 0, 0, 0);
        oA1 = __builtin_amdgcn_mfma_f32_16x16x32_bf16(vta1, pu.v, oA1, 0, 0, 0);
    }

    f32x4 o0 = oA0 + oB0, o1 = oA1 + oB1;
    float ll = llA + llB;
    ll += __shfl_xor(ll, 16);
    ll += __shfl_xor(ll, 32);
    float inv = 1.f / ll;
    unsigned w0 = cvtpk(o0[0] * inv, o0[1] * inv);
    unsigned w1 = cvtpk(o0[2] * inv, o0[3] * inv);
    unsigned w2 = cvtpk(o1[0] * inv, o1[1] * inv);
    unsigned w3 = cvtpk(o1[2] * inv, o1[3] * inv);
    uint2 st0; st0.x = w0; st0.y = w1;
    uint2 st1; st1.x = w2; st1.y = w3;
    *(uint2*)(out + qrow * D + h * DH + q4 * 4) = st0;
    *(uint2*)(out + qrow * D + h * DH + 16 + q4 * 4) = st1;
}

extern "C" void kernel_launch(void* const* d_in, const int* in_sizes, int n_in,
                              void* d_out, int out_size, void* d_ws, size_t ws_size,
                              hipStream_t stream) {
    const float* meas_xy = (const float*)d_in[0];
    const float* meas_v  = (const float*)d_in[1];
    const float* bs_xy   = (const float*)d_in[2];
    const int*   task_id = (const int*)d_in[3];
    const float* city    = (const float*)d_in[4];
    const float* mp_w1 = (const float*)d_in[5];  const float* mp_b1 = (const float*)d_in[6];
    const float* mp_w2 = (const float*)d_in[7];  const float* mp_b2 = (const float*)d_in[8];
    const float* bp_w1 = (const float*)d_in[9];  const float* bp_b1 = (const float*)d_in[10];
    const float* bp_w2 = (const float*)d_in[11]; const float* bp_b2 = (const float*)d_in[12];
    const float* env_w1 = (const float*)d_in[13]; const float* env_b1 = (const float*)d_in[14];
    const float* env_w2 = (const float*)d_in[15]; const float* env_b2 = (const float*)d_in[16];
    const float* env_w3 = (const float*)d_in[17]; const float* env_b3 = (const float*)d_in[18];
    const float* task_emb = (const float*)d_in[19];
    const float* tp_w = (const float*)d_in[20]; const float* tp_b = (const float*)d_in[21];
    const float* grid_pos = (const float*)d_in[22];
    const float* dens_w = (const float*)d_in[23]; const float* dens_b = (const float*)d_in[24];
    const float* ln1_w = (const float*)d_in[25]; const float* ln1_b = (const float*)d_in[26];
    const float* wq = (const float*)d_in[27]; const float* bq = (const float*)d_in[28];
    const float* wk = (const float*)d_in[29]; const float* bk = (const float*)d_in[30];
    const float* wv = (const float*)d_in[31]; const float* bv = (const float*)d_in[32];
    const float* wo = (const float*)d_in[33]; const float* bo = (const float*)d_in[34];
    const float* ln2_w = (const float*)d_in[35]; const float* ln2_b = (const float*)d_in[36];
    const float* ff_w1 = (const float*)d_in[37]; const float* ff_b1 = (const float*)d_in[38];
    const float* ff_w2 = (const float*)d_in[39]; const float* ff_b2 = (const float*)d_in[40];
    const float* tfp_w = (const float*)d_in[41]; const float* tfp_b = (const float*)d_in[42];
    const float* head_w = (const float*)d_in[43]; const float* head_b = (const float*)d_in[44];
    float* out = (float*)d_out;

    float* ws = (float*)d_ws;
    size_t off = 0;
    float* src_xy = ws + off; off += (size_t)B * NS * 2 + 128;
    float* dens   = ws + off; off += (size_t)B * KK;
    float* tvec   = ws + off; off += (size_t)B * D;
    float* h1     = ws + off; off += (size_t)B * EC * KK;
    float* grid   = ws + off; off += (size_t)B * KK * D;
    unsigned short* srcbf = (unsigned short*)(ws + off); off += (size_t)MSRCP * D / 2;
    unsigned short* khd   = (unsigned short*)(ws + off); off += (size_t)B * 8 * 544 * 32 / 2;
    unsigned short* vch   = (unsigned short*)(ws + off); off += (size_t)B * 8 * 17 * 1024 / 2;
    float* qreg   = ws + off; off += (size_t)B * KK * D / 2;   // qbf; hosts h2 f32 early
    unsigned short* qbf = (unsigned short*)qreg;
    float* h2     = qreg;
    unsigned short* xbf    = (unsigned short*)(ws + off); off += (size_t)B * KK * D / 2;
    unsigned short* attnbf = (unsigned short*)(ws + off); off += (size_t)B * KK * D / 2;
    unsigned short* ndbf   = (unsigned short*)(ws + off); off += (size_t)B * 64 * 34816 / 2;  // 17.8 MB
    unsigned short* hidbf  = (unsigned short*)(ws + off); off += (size_t)B * KK * DFF / 2;    // 32 MB
    unsigned short* wqT  = (unsigned short*)(ws + off); off += (size_t)LYR * D * D / 2;
    unsigned short* kvT  = (unsigned short*)(ws + off); off += (size_t)LYR * 512 * D / 2;
    unsigned short* woT  = (unsigned short*)(ws + off); off += (size_t)LYR * D * D / 2;
    unsigned short* ff1T = (unsigned short*)(ws + off); off += (size_t)LYR * D * DFF / 2;
    unsigned short* ff2T = (unsigned short*)(ws + off); off += (size_t)LYR * DFF * D / 2;
    unsigned short* tfpT = (unsigned short*)(ws + off); off += (size_t)T * D * D / 2;
    float* kvbias = ws + off; off += (size_t)LYR * 512;
    (void)ws_size; (void)n_in; (void)in_sizes; (void)out_size;

    const int M = B * KK;       // 16384

    pre1_k<<<6116, 256, 0, stream>>>(
        wq, wk, wv, wo, ff_w1, ff_w2, tfp_w, bk, bv,
        wqT, kvT, woT, ff1T, ff2T, tfpT, kvbias,
        meas_xy, meas_v, bs_xy, mp_w1, mp_b1, mp_w2, mp_b2,
        bp_w1, bp_b1, bp_w2, bp_b2, srcbf, src_xy,
        dens, city, env_w1, env_b1, h1,
        task_emb, task_id, tp_w, tp_b, tvec, khd, vch);
    conv2_k<<<512, 256, 0, stream>>>(h1, env_w2, env_b2, h2);
    pre2_k<<<2368, 256, 0, stream>>>(h2, env_w3, env_b3, grid_pos, tvec, grid,
                                     src_xy, ndbf, out, head_b);

    for (int l = 0; l < LYR; l++) {
        dens_ln_k<1><<<M / 4, 256, 0, stream>>>(grid, dens, dens_w + l * D, dens_b + l * D,
                                                ln1_w + l * D, ln1_b + l * D, xbf);
        qkv_k<<<dim3(12, 256), 256, 0, stream>>>(
            xbf, wqT + (size_t)l * D * D, bq + l * D, qbf,
            srcbf, kvT + (size_t)l * 512 * D, kvbias + l * 512, khd, vch);
        attn_mfma<<<B * NH * 64, 256, 0, stream>>>(qbf, khd, vch, ndbf, attnbf);
        gemm_k<0, 1, 0, 0, 0><<<dim3(4, 256), 256, 0, stream>>>(
            attnbf, woT + (size_t)l * D * D, bo + l * D, grid, M, D, D, nullptr, nullptr, nullptr);
        dens_ln_k<0><<<M / 4, 256, 0, stream>>>(grid, nullptr, nullptr, nullptr,
                                                ln2_w + l * D, ln2_b + l * D, xbf);
        gemm_k<1, 0, 1, 0, 0><<<dim3(16, 256), 256, 0, stream>>>(
            xbf, ff1T + (size_t)l * D * DFF, ff_b1 + l * DFF, hidbf, M, D, DFF,
            nullptr, nullptr, nullptr);
        if (l == 0) {
            gemm_k<0, 1, 0, 0, 0><<<dim3(4, 256), 256, 0, stream>>>(
                hidbf, ff2T + (size_t)l * DFF * D, ff_b2 + l * D, grid, M, DFF, D,
                nullptr, nullptr, nullptr);
        } else {
            gemm_k<0, 1, 0, 0, 1><<<dim3(4, 256), 256, 0, stream>>>(
                hidbf, ff2T + (size_t)l * DFF * D, ff_b2 + l * D, grid, M, DFF, D,
                nullptr, nullptr, xbf);
        }
    }
    gemm_k<1, 0, 0, 1, 0><<<dim3(4, 256), 256, 0, stream>>>(
        xbf, tfpT, tfp_b, out, M, D, D, task_id, head_w, nullptr);
}

// Round 13
// 575.345 us; speedup vs baseline: 1.0580x; 1.0580x over previous
//
#include <hip/hip_runtime.h>
#include <hip/hip_bf16.h>
#include <math.h>

#define D 256
#define NH 8
#define DH 32
#define LYR 2
#define G 64
#define KK 4096
#define T 4
#define EC 32
#define B 4
#define N 512
#define CITY 256
#define DFF 1024
#define NS 513    // N + 1 bs token
#define NSP 544   // 17 * 32 padded token count
#define MSRC 2052 // B * NS
#define MSRCP 2176 // padded to 34*64
#define ISQ 0.17677669529663687f
#define LOG2E 1.4426950408889634f

typedef short bf16x8 __attribute__((ext_vector_type(8)));
typedef float f32x4 __attribute__((ext_vector_type(4)));

__device__ __forceinline__ float gelu_f(float x) {
    const float c = 0.7978845608028654f;
    float x3 = x * x * x;
    return 0.5f * x * (1.f + tanhf(c * (x + 0.044715f * x3)));
}

__device__ __forceinline__ unsigned short f2bf(float f) {
    unsigned int u = __float_as_uint(f);
    unsigned int r = (u + 0x7FFFu + ((u >> 16) & 1u)) >> 16;
    return (unsigned short)r;
}

__device__ __forceinline__ float bf2f(unsigned short u) {
    return __uint_as_float((unsigned)u << 16);
}

__device__ __forceinline__ unsigned cvtpk(float a, float b) {
    unsigned r;
    asm("v_cvt_pk_bf16_f32 %0, %1, %2" : "=v"(r) : "v"(a), "v"(b));
    return r;
}

__device__ __forceinline__ void gl2lds16(const unsigned short* g, unsigned short* l) {
    __builtin_amdgcn_global_load_lds(
        (const __attribute__((address_space(1))) unsigned int*)g,
        (__attribute__((address_space(3))) unsigned int*)l, 16, 0, 0);
}

// ================= pre1: transposes + tok_mlp + density + conv1 + tvec + K/V pad zero ===========
__global__ __launch_bounds__(256) void pre1_k(
    const float* __restrict__ wq, const float* __restrict__ wk,
    const float* __restrict__ wv, const float* __restrict__ wo,
    const float* __restrict__ ff1, const float* __restrict__ ff2,
    const float* __restrict__ tfp,
    const float* __restrict__ bk, const float* __restrict__ bv,
    unsigned short* __restrict__ wqT, unsigned short* __restrict__ kvT,
    unsigned short* __restrict__ woT, unsigned short* __restrict__ ff1T,
    unsigned short* __restrict__ ff2T, unsigned short* __restrict__ tfpT,
    float* __restrict__ kvbias,
    const float* __restrict__ meas_xy, const float* __restrict__ meas_v,
    const float* __restrict__ bs_xy,
    const float* __restrict__ mp_w1, const float* __restrict__ mp_b1,
    const float* __restrict__ mp_w2, const float* __restrict__ mp_b2,
    const float* __restrict__ bp_w1, const float* __restrict__ bp_b1,
    const float* __restrict__ bp_w2, const float* __restrict__ bp_b2,
    unsigned short* __restrict__ srcbf, float* __restrict__ src_xy,
    float* __restrict__ dens,
    const float* __restrict__ city, const float* __restrict__ env_w1,
    const float* __restrict__ env_b1, float* __restrict__ h1,
    const float* __restrict__ task_emb, const int* __restrict__ task_id,
    const float* __restrict__ tp_w, const float* __restrict__ tp_b,
    float* __restrict__ tvec,
    unsigned short* __restrict__ khd, unsigned short* __restrict__ vch)
{
    __shared__ float sh[1088];
    int bx = blockIdx.x;
    int tid = threadIdx.x;
    if (bx < 1792) {
        const float* src; unsigned short* dst;
        int Kd, Nn, nmat, rowOff = 0, t; size_t matStride;
        if (bx < 512) {
            int job = bx >> 7; t = bx & 127;
            Kd = 256; Nn = 256; nmat = 2;
            if (job == 0)      { src = wq; dst = wqT; matStride = 65536; }
            else if (job == 1) { src = wk; dst = kvT; matStride = 131072; }
            else if (job == 2) { src = wv; dst = kvT; matStride = 131072; rowOff = 256; }
            else               { src = wo; dst = woT; matStride = 65536; }
            if ((t & 63) == 0 && job == 1) kvbias[(t >> 6) * 512 + tid] = bk[(t >> 6) * 256 + tid];
            if ((t & 63) == 0 && job == 2) kvbias[(t >> 6) * 512 + 256 + tid] = bv[(t >> 6) * 256 + tid];
        } else if (bx < 1024) { t = bx - 512;  src = ff1; dst = ff1T; Kd = 256;  Nn = 1024; nmat = 2; matStride = 262144; }
        else if (bx < 1536)   { t = bx - 1024; src = ff2; dst = ff2T; Kd = 1024; Nn = 256;  nmat = 2; matStride = 262144; }
        else                  { t = bx - 1536; src = tfp; dst = tfpT; Kd = 256;  Nn = 256;  nmat = 4; matStride = 65536; }
        int tn = Nn / 32, perMat = tn * (Kd / 32);
        int mat = t / perMat;
        int rem = t - mat * perMat;
        int nb = (rem % tn) * 32, kb = (rem / tn) * 32;
        const float* s = src + (size_t)mat * Kd * Nn;
        unsigned short* d = dst + (size_t)mat * matStride;
        float (*tb)[33] = (float (*)[33])sh;
        int tx = tid & 31, ty = tid >> 5;
        #pragma unroll
        for (int i = 0; i < 4; i++)
            tb[ty + i * 8][tx] = s[(size_t)(kb + ty + i * 8) * Nn + nb + tx];
        __syncthreads();
        #pragma unroll
        for (int i = 0; i < 4; i++)
            d[(size_t)(rowOff + nb + ty + i * 8) * Kd + kb + tx] = f2bf(tb[tx][ty + i * 8]);
    } else if (bx < 3968) {
        int id = bx - 1792;
        int dd = tid;
        if (id >= B * N + B) {
            srcbf[(size_t)id * D + dd] = 0;
            return;
        }
        float* hid = sh;
        int row;
        const float *w1, *b1, *w2, *b2;
        float x0, x1, x2 = 0.f;
        int nin;
        if (id < B * N) {
            int b = id >> 9, n = id & 511;
            x0 = meas_xy[(b * N + n) * 2 + 0];
            x1 = meas_xy[(b * N + n) * 2 + 1];
            x2 = meas_v[b * N + n];
            w1 = mp_w1; b1 = mp_b1; w2 = mp_w2; b2 = mp_b2; nin = 3;
            row = b * NS + n;
        } else {
            int b = id - B * N;
            x0 = bs_xy[b * 2 + 0];
            x1 = bs_xy[b * 2 + 1];
            w1 = bp_w1; b1 = bp_b1; w2 = bp_w2; b2 = bp_b2; nin = 2;
            row = b * NS + N;
        }
        float h = x0 * w1[dd] + x1 * w1[D + dd] + b1[dd];
        if (nin == 3) h += x2 * w1[2 * D + dd];
        hid[dd] = gelu_f(h);
        __syncthreads();
        float o = b2[dd];
        for (int j = 0; j < D; j++) o += hid[j] * w2[j * D + dd];
        srcbf[(size_t)row * D + dd] = f2bf(o);
        if (dd == 0) { src_xy[row * 2 + 0] = x0; src_xy[row * 2 + 1] = x1; }
    } else if (bx < 4032) {
        int blk = bx - 3968;
        int b = blk >> 4, kc = blk & 15;
        int k = kc * 256 + tid;
        float* mx = sh; float* my = sh + 512;
        for (int i = tid; i < N; i += 256) {
            mx[i] = meas_xy[(b * N + i) * 2 + 0];
            my[i] = meas_xy[(b * N + i) * 2 + 1];
        }
        __syncthreads();
        float gx = ((k & 63) + 0.5f) / 64.f;
        float gy = ((k >> 6) + 0.5f) / 64.f;
        float s = 0.f;
        for (int n = 0; n < N; n++) {
            float dx = gx - mx[n], dy = gy - my[n];
            s += __expf(-(dx * dx + dy * dy) * 78.125f);
        }
        dens[b * KK + k] = s * (1.f / (float)N);
    } else if (bx < 6080) {
        int i = (bx - 4032) * 256 + tid;
        int x = i & 63, y = (i >> 6) & 63, c = (i >> 12) & 31, b = i >> 17;
        float s = env_b1[c];
        for (int ky = 0; ky < 3; ky++) {
            int yy = y + ky - 1;
            if (yy < 0 || yy >= G) continue;
            for (int kx = 0; kx < 3; kx++) {
                int xx = x + kx - 1;
                if (xx < 0 || xx >= G) continue;
                s += city[(b * CITY + yy * 4) * CITY + xx * 4] * env_w1[c * 9 + ky * 3 + kx];
            }
        }
        h1[i] = gelu_f(s);
    } else if (bx < 6084) {
        int b = bx - 6080;
        float* e = sh;
        e[tid] = task_emb[task_id[b] * D + tid];
        __syncthreads();
        float s = tp_b[tid];
        for (int j = 0; j < D; j++) s += e[j] * tp_w[j * D + tid];
        tvec[b * D + tid] = s;
    } else {
        int bh = bx - 6084;     // 0..31
        unsigned short* kp = khd + ((size_t)bh * 544 + 513) * 32;
        for (int i = tid; i < 992; i += 256) kp[i] = 0;
        unsigned short* vp = vch + ((size_t)bh * 17 + 16) * 1024;
        for (int i = tid; i < 1024; i += 256) vp[i] = 0;
    }
}

// ================= conv2: branchless, 4 c_out/thread, ci-pipelined =================
__global__ __launch_bounds__(256) void conv2_k(
    const float* __restrict__ h1, const float* __restrict__ w,
    const float* __restrict__ bias, float* __restrict__ h2) {
    int blk = blockIdx.x;
    int yt = blk & 15, cg = (blk >> 4) & 7, b = blk >> 7;
    int x = threadIdx.x & 63, y = yt * 4 + (threadIdx.x >> 6);
    int c0 = cg * 4;
    float flag[9];
    int off[9];
    #pragma unroll
    for (int ky = 0; ky < 3; ky++) {
        int yy = y + ky - 1;
        bool vy = (yy >= 0 && yy < G);
        int yc = min(max(yy, 0), G - 1);
        #pragma unroll
        for (int kx = 0; kx < 3; kx++) {
            int xx = x + kx - 1;
            bool vx = (xx >= 0 && xx < G);
            int xc = min(max(xx, 0), G - 1);
            flag[ky * 3 + kx] = (vy && vx) ? 1.f : 0.f;
            off[ky * 3 + kx] = yc * G + xc;
        }
    }
    const float* hp = h1 + ((size_t)(b * EC) << 12);
    float acc[4] = {bias[c0], bias[c0 + 1], bias[c0 + 2], bias[c0 + 3]};
    float v[9], nv[9];
    #pragma unroll
    for (int t = 0; t < 9; t++) v[t] = hp[off[t]] * flag[t];
    for (int ci = 0; ci < EC; ci++) {
        if (ci < EC - 1) {
            const float* hn = hp + ((size_t)(ci + 1) << 12);
            #pragma unroll
            for (int t = 0; t < 9; t++) nv[t] = hn[off[t]] * flag[t];
        }
        #pragma unroll
        for (int cc = 0; cc < 4; cc++) {
            const float* wp = w + ((size_t)(c0 + cc) * EC + ci) * 9;
            #pragma unroll
            for (int t = 0; t < 9; t++) acc[cc] += v[t] * wp[t];
        }
        #pragma unroll
        for (int t = 0; t < 9; t++) v[t] = nv[t];
    }
    size_t obase = (((size_t)(b * EC + c0)) << 12) + y * G + x;
    #pragma unroll
    for (int cc = 0; cc < 4; cc++)
        h2[obase + ((size_t)cc << 12)] = gelu_f(acc[cc]);
}

// ================= pre2: grid_init + swizzled nd (pre-scaled by log2e) + out_init =================
// ndL layout: [b][qt64][c17][half2][q4(4)][query16x4(64)][r4] ushort
__global__ __launch_bounds__(256) void pre2_k(
    const float* __restrict__ h2, const float* __restrict__ w3,
    const float* __restrict__ b3, const float* __restrict__ grid_pos,
    const float* __restrict__ tvec, float* __restrict__ grid,
    const float* __restrict__ sxy, unsigned short* __restrict__ nd,
    float* __restrict__ out, const float* __restrict__ head_b)
{
    __shared__ float sh[1088];
    int bx = blockIdx.x;
    int tid = threadIdx.x;
    if (bx < 2048) {
        int b = bx >> 9, k0 = (bx & 511) * 8;
        float (*h2s)[8] = (float (*)[8])sh;
        h2s[tid >> 3][tid & 7] = h2[(((size_t)b * EC + (tid >> 3)) << 12) + k0 + (tid & 7)];
        float w3r[32];
        #pragma unroll
        for (int c4 = 0; c4 < 8; c4++) {
            float4 w4 = *(const float4*)(w3 + tid * 32 + c4 * 4);
            w3r[c4 * 4 + 0] = w4.x; w3r[c4 * 4 + 1] = w4.y;
            w3r[c4 * 4 + 2] = w4.z; w3r[c4 * 4 + 3] = w4.w;
        }
        float base = b3[tid] + tvec[b * D + tid];
        __syncthreads();
        #pragma unroll
        for (int j = 0; j < 8; j++) {
            float s = base + grid_pos[(size_t)(k0 + j) * D + tid];
            #pragma unroll
            for (int ci = 0; ci < 32; ci++) s += h2s[ci][j] * w3r[ci];
            grid[((size_t)b * KK + k0 + j) * D + tid] = s;
        }
    } else if (bx < 2304) {
        int q = bx - 2048;          // b*64 + qt
        int b = q >> 6, qt = q & 63;
        float* sxs = sh; float* sys = sh + 544;
        for (int i = tid; i < 544; i += 256) {
            float x = 0.f, y = 0.f;
            if (i < NS) { x = sxy[(b * NS + i) * 2]; y = sxy[(b * NS + i) * 2 + 1]; }
            sxs[i] = x; sys[i] = y;
        }
        __syncthreads();
        unsigned short* base = nd + (size_t)q * 34816;
        for (int c = 0; c < 17; c++) {
            #pragma unroll
            for (int it = 0; it < 2; it++) {
                int lin = it * 256 + tid;
                int w16 = lin & 63, q4 = (lin >> 6) & 3, half = lin >> 8;
                int qidx = qt * 64 + w16;
                float gx = ((qidx & 63) + 0.5f) * (1.f / 64.f);
                float gy = ((qidx >> 6) + 0.5f) * (1.f / 64.f);
                unsigned short vs[4];
                #pragma unroll
                for (int r = 0; r < 4; r++) {
                    int tok = c * 32 + half * 16 + q4 * 4 + r;
                    float val;
                    if (tok < NS) {
                        float dx = gx - sxs[tok], dy = gy - sys[tok];
                        val = -sqrtf(dx * dx + dy * dy);
                    } else val = -1e4f;
                    vs[r] = f2bf(val * LOG2E);   // pre-scaled for exp2
                }
                ushort4 o; o.x = vs[0]; o.y = vs[1]; o.z = vs[2]; o.w = vs[3];
                *(ushort4*)(base + (size_t)c * 2048 + lin * 4) = o;
            }
        }
    } else {
        out[(bx - 2304) * 256 + tid] = head_b[0];
    }
}

// ================= fused density-inject + layernorm -> bf16 =================
template <int DENS>
__global__ __launch_bounds__(256) void dens_ln_k(
    float* __restrict__ grid, const float* __restrict__ dens,
    const float* __restrict__ dw, const float* __restrict__ db,
    const float* __restrict__ lw, const float* __restrict__ lb,
    unsigned short* __restrict__ y) {
    int row = blockIdx.x * 4 + (threadIdx.x >> 6);
    int lane = threadIdx.x & 63;
    float* gp = grid + (size_t)row * D + lane * 4;
    float4 v = *(float4*)gp;
    if (DENS) {
        float de = dens[row];
        float4 w4 = *(const float4*)(dw + lane * 4);
        float4 b4 = *(const float4*)(db + lane * 4);
        v.x += de * w4.x + b4.x; v.y += de * w4.y + b4.y;
        v.z += de * w4.z + b4.z; v.w += de * w4.w + b4.w;
        *(float4*)gp = v;
    }
    float s = v.x + v.y + v.z + v.w;
    #pragma unroll
    for (int o = 32; o > 0; o >>= 1) s += __shfl_xor(s, o);
    float mean = s * (1.f / D);
    float cx = v.x - mean, cy = v.y - mean, cz = v.z - mean, cw = v.w - mean;
    float q = cx * cx + cy * cy + cz * cz + cw * cw;
    #pragma unroll
    for (int o = 32; o > 0; o >>= 1) q += __shfl_xor(q, o);
    float inv = rsqrtf(q * (1.f / D) + 1e-5f);
    float4 lwv = *(const float4*)(lw + lane * 4);
    float4 lbv = *(const float4*)(lb + lane * 4);
    ushort4 o4;
    o4.x = f2bf(cx * inv * lwv.x + lbv.x);
    o4.y = f2bf(cy * inv * lwv.y + lbv.y);
    o4.z = f2bf(cz * inv * lwv.z + lbv.z);
    o4.w = f2bf(cw * inv * lwv.w + lbv.w);
    *(ushort4*)(y + (size_t)row * D + lane * 4) = o4;
}

// ================= GEMM core: C[M,N] = A[M,K] @ Wt[N,K]^T + bias =================
// BM=64, BN=64, BK=64, double-buffered LDS.
template <int GELU, int ACCUM, int OBF, int TFPH, int STBF, int KVT = 0>
__device__ __forceinline__ void gemm_core(
    const unsigned short* __restrict__ A, const unsigned short* __restrict__ Wt,
    const float* __restrict__ bias, void* __restrict__ Cv,
    int M, int K, int Nn, int bn, int bm,
    const float* __restrict__ hw, unsigned short* __restrict__ Xb, float scale,
    unsigned short* As, unsigned short* Bs) {
    int tid = threadIdx.x;
    int wave = tid >> 6, lane = tid & 63;
    int q4 = lane >> 4, lr = lane & 15;
    int wn = wave * 16;
    int srow = tid >> 2, sk8 = (tid & 3) * 8;
    const unsigned short* Ap  = A  + (size_t)(bm + srow) * K + sk8;
    const unsigned short* Bp0 = Wt + (size_t)(bn + srow) * K + sk8;
    unsigned short* AsD = As + tid * 8;
    unsigned short* BsD = Bs + tid * 8;
    f32x4 acc[4] = {};

    gl2lds16(Ap,       AsD);
    gl2lds16(Ap + 32,  AsD + 2048);
    gl2lds16(Bp0,      BsD);
    gl2lds16(Bp0 + 32, BsD + 2048);

    int nk = K >> 6;
    for (int ki = 0; ki < nk; ki++) {
        __syncthreads();
        if (ki + 1 < nk) {
            int k0 = (ki + 1) << 6;
            int nb = ((ki + 1) & 1) * 4096;
            gl2lds16(Ap + k0,       AsD + nb);
            gl2lds16(Ap + k0 + 32,  AsD + nb + 2048);
            gl2lds16(Bp0 + k0,      BsD + nb);
            gl2lds16(Bp0 + k0 + 32, BsD + nb + 2048);
        }
        int cb = (ki & 1) * 4096;
        #pragma unroll
        for (int ks = 0; ks < 2; ks++) {
            bf16x8 af[4], bf;
            #pragma unroll
            for (int i = 0; i < 4; i++)
                af[i] = *(const bf16x8*)&As[cb + ks * 2048 + (i * 16 + lr) * 32 + q4 * 8];
            bf = *(const bf16x8*)&Bs[cb + ks * 2048 + (wn + lr) * 32 + q4 * 8];
            #pragma unroll
            for (int i = 0; i < 4; i++)
                acc[i] = __builtin_amdgcn_mfma_f32_16x16x32_bf16(af[i], bf, acc[i], 0, 0, 0);
        }
    }

    if (KVT) {
        int gc = bn + wn + lr;
        float bv = bias[gc];
        bool isV = gc >= 256;
        #pragma unroll
        for (int i = 0; i < 4; i++) {
            #pragma unroll
            for (int r = 0; r < 4; r++) {
                int gr = bm + i * 16 + q4 * 4 + r;
                if (gr < MSRC) {
                    float v = acc[i][r] + bv;
                    int bb = gr / NS;
                    int tok = gr - bb * NS;
                    if (!isV) {
                        int h = gc >> 5, dh = gc & 31;
                        ((unsigned short*)Cv)[(((size_t)(bb * 8 + h) * 544) + tok) * 32 + dh] = f2bf(v);
                    } else {
                        int gcv = gc - 256;
                        int h = gcv >> 5, dh = gcv & 31;
                        int c = tok >> 5, t32 = tok & 31;
                        Xb[((((size_t)(bb * 8 + h) * 17 + c) * 32 + dh)) * 32 + t32] = f2bf(v);
                    }
                }
            }
        }
        return;
    }

    if (TFPH) {
        int gc = bn + wn + lr;
        float bv = bias[gc];
        float hv = hw[gc];
        #pragma unroll
        for (int i = 0; i < 4; i++) {
            #pragma unroll
            for (int r = 0; r < 4; r++) {
                float s = gelu_f(acc[i][r] + bv) * hv;
                s += __shfl_xor(s, 1); s += __shfl_xor(s, 2);
                s += __shfl_xor(s, 4); s += __shfl_xor(s, 8);
                if (lr == 0)
                    atomicAdd((float*)Cv + (bm + i * 16 + q4 * 4 + r), s);
            }
        }
        return;
    }

    int gc = bn + wn + lr;
    float bv = bias[gc];
    #pragma unroll
    for (int i = 0; i < 4; i++) {
        #pragma unroll
        for (int r = 0; r < 4; r++) {
            int gr = bm + i * 16 + q4 * 4 + r;
            if (gr < M) {
                float v = (acc[i][r] + bv) * scale;
                if (GELU) v = gelu_f(v);
                size_t idx = (size_t)gr * Nn + gc;
                if (OBF) {
                    ((unsigned short*)Cv)[idx] = f2bf(v);
                } else if (ACCUM) {
                    float nv = ((float*)Cv)[idx] + v;
                    ((float*)Cv)[idx] = nv;
                    if (STBF) Xb[idx] = f2bf(nv);
                } else {
                    ((float*)Cv)[idx] = v;
                }
            }
        }
    }
}

template <int GELU, int ACCUM, int OBF, int TFPH, int STBF>
__global__ __launch_bounds__(256) void gemm_k(
    const unsigned short* __restrict__ A, const unsigned short* __restrict__ Wt0,
    const float* __restrict__ bias0, void* __restrict__ Cv,
    int M, int K, int Nn, const int* __restrict__ task_id,
    const float* __restrict__ hw, unsigned short* __restrict__ Xb) {
    __shared__ unsigned short As[8192];
    __shared__ unsigned short Bs[8192];
    const unsigned short* Wt = Wt0;
    const float* bias = bias0;
    int bm = blockIdx.y * 64;
    if (TFPH) { int t = task_id[bm >> 12]; Wt += (size_t)t * D * D; bias += t * D; }
    gemm_core<GELU, ACCUM, OBF, TFPH, STBF>(A, Wt, bias, Cv, M, K, Nn,
                                            blockIdx.x * 64, bm, hw, Xb, 1.f, As, Bs);
}

// fused Q + KV projections. Q scaled by isq*log2e (softmax uses exp2); K -> khd, V -> vch.
__global__ __launch_bounds__(256) void qkv_k(
    const unsigned short* __restrict__ xbf, const unsigned short* __restrict__ wqT,
    const float* __restrict__ bq, unsigned short* __restrict__ qbf,
    const unsigned short* __restrict__ srcbf, const unsigned short* __restrict__ kvT,
    const float* __restrict__ kvb, unsigned short* __restrict__ khd,
    unsigned short* __restrict__ vch) {
    __shared__ unsigned short As[8192];
    __shared__ unsigned short Bs[8192];
    if (blockIdx.x < 4) {
        gemm_core<0, 0, 1, 0, 0, 0>(xbf, wqT, bq, qbf, B * KK, D, D,
                                    blockIdx.x * 64, blockIdx.y * 64, nullptr, nullptr,
                                    ISQ * LOG2E, As, Bs);
    } else {
        if (blockIdx.y >= MSRCP / 64) return;
        gemm_core<0, 0, 1, 0, 0, 1>(srcbf, kvT, kvb, khd, MSRC, D, 512,
                                    (blockIdx.x - 4) * 64, blockIdx.y * 64, nullptr, vch, 1.f, As, Bs);
    }
}

// ================= MFMA flash cross-attention, zero-LDS, dense, depth-1 pipeline =================
// S' = K Q^T (query=col, q pre-scaled isq*log2e), p = exp2(s + nd2); O^T = V^T P'.
__global__ __launch_bounds__(256) void attn_mfma(
    const unsigned short* __restrict__ qb,
    const unsigned short* __restrict__ khd,
    const unsigned short* __restrict__ vch,
    const unsigned short* __restrict__ ndL,
    unsigned short* __restrict__ out)
{
    int bid = blockIdx.x;                    // b*512 + h*64 + qt
    int qt = bid & 63, h = (bid >> 6) & 7, b = bid >> 9;
    int tid = threadIdx.x, wave = tid >> 6, lane = tid & 63;
    int q4 = lane >> 4, lr = lane & 15;

    int kbase = qt * 64 + wave * 16;
    size_t qrow = (size_t)(b * KK + kbase + lr);
    bf16x8 qf = *(const bf16x8*)(qb + qrow * D + h * DH + q4 * 8);
    const unsigned short* kp0 = khd + ((size_t)(b * 8 + h) * 544) * 32 + lr * 32 + q4 * 8;
    const unsigned short* vb0 = vch + ((size_t)(b * 8 + h) * 17) * 1024 + lr * 32 + q4 * 8;
    const unsigned short* ndp = ndL + ((size_t)(b * 64 + qt)) * 34816 + q4 * 256 + (wave * 16 + lr) * 4;

    float ll0 = 0.f, ll1 = 0.f;
    f32x4 o0 = {0.f, 0.f, 0.f, 0.f}, o1 = {0.f, 0.f, 0.f, 0.f};
    int sA = ((lane >> 4) & 1) * 32 + lr;
    int sB = sA + 16;
    bool hi = (lane & 32) != 0;

    bf16x8 kf0 = *(const bf16x8*)kp0;
    bf16x8 kf1 = *(const bf16x8*)(kp0 + 512);
    bf16x8 vt0 = *(const bf16x8*)vb0;
    bf16x8 vt1 = *(const bf16x8*)(vb0 + 512);
    ushort4 n0v = *(const ushort4*)ndp;
    ushort4 n1v = *(const ushort4*)(ndp + 1024);

    for (int c = 0; c < 17; c++) {
        bf16x8 ck0 = kf0, ck1 = kf1, cv0 = vt0, cv1 = vt1;
        ushort4 cn0 = n0v, cn1 = n1v;
        if (c < 16) {
            size_t co = (size_t)(c + 1) * 1024;
            kf0 = *(const bf16x8*)(kp0 + co);
            kf1 = *(const bf16x8*)(kp0 + co + 512);
            vt0 = *(const bf16x8*)(vb0 + co);
            vt1 = *(const bf16x8*)(vb0 + co + 512);
            n0v = *(const ushort4*)(ndp + (size_t)(c + 1) * 2048);
            n1v = *(const ushort4*)(ndp + (size_t)(c + 1) * 2048 + 1024);
        }
        f32x4 s0 = {0.f, 0.f, 0.f, 0.f}, s1 = {0.f, 0.f, 0.f, 0.f};
        s0 = __builtin_amdgcn_mfma_f32_16x16x32_bf16(ck0, qf, s0, 0, 0, 0);  // S'[tok][qry]
        s1 = __builtin_amdgcn_mfma_f32_16x16x32_bf16(ck1, qf, s1, 0, 0, 0);
        float p0[4], p1[4];
        p0[0] = __builtin_amdgcn_exp2f(s0[0] + bf2f(cn0.x));
        p0[1] = __builtin_amdgcn_exp2f(s0[1] + bf2f(cn0.y));
        p0[2] = __builtin_amdgcn_exp2f(s0[2] + bf2f(cn0.z));
        p0[3] = __builtin_amdgcn_exp2f(s0[3] + bf2f(cn0.w));
        p1[0] = __builtin_amdgcn_exp2f(s1[0] + bf2f(cn1.x));
        p1[1] = __builtin_amdgcn_exp2f(s1[1] + bf2f(cn1.y));
        p1[2] = __builtin_amdgcn_exp2f(s1[2] + bf2f(cn1.z));
        p1[3] = __builtin_amdgcn_exp2f(s1[3] + bf2f(cn1.w));
        ll0 += (p0[0] + p0[1]) + (p0[2] + p0[3]);
        ll1 += (p1[0] + p1[1]) + (p1[2] + p1[3]);
        unsigned pk0 = cvtpk(p0[0], p0[1]);
        unsigned pk1 = cvtpk(p0[2], p0[3]);
        unsigned pk2 = cvtpk(p1[0], p1[1]);
        unsigned pk3 = cvtpk(p1[2], p1[3]);
        unsigned a0 = (unsigned)__shfl((int)pk0, sA), c0 = (unsigned)__shfl((int)pk2, sA);
        unsigned a1 = (unsigned)__shfl((int)pk1, sA), c1 = (unsigned)__shfl((int)pk3, sA);
        unsigned a2 = (unsigned)__shfl((int)pk0, sB), c2 = (unsigned)__shfl((int)pk2, sB);
        unsigned a3 = (unsigned)__shfl((int)pk1, sB), c3 = (unsigned)__shfl((int)pk3, sB);
        union { unsigned u[4]; bf16x8 v; } pu;
        pu.u[0] = hi ? c0 : a0;
        pu.u[1] = hi ? c1 : a1;
        pu.u[2] = hi ? c2 : a2;
        pu.u[3] = hi ? c3 : a3;
        o0 = __builtin_amdgcn_mfma_f32_16x16x32_bf16(cv0, pu.v, o0, 0, 0, 0);  // O^T[dh][qry]
        o1 = __builtin_amdgcn_mfma_f32_16x16x32_bf16(cv1, pu.v, o1, 0, 0, 0);
    }

    float ll = ll0 + ll1;
    ll += __shfl_xor(ll, 16);
    ll += __shfl_xor(ll, 32);
    float inv = 1.f / ll;
    unsigned w0 = cvtpk(o0[0] * inv, o0[1] * inv);
    unsigned w1 = cvtpk(o0[2] * inv, o0[3] * inv);
    unsigned w2 = cvtpk(o1[0] * inv, o1[1] * inv);
    unsigned w3 = cvtpk(o1[2] * inv, o1[3] * inv);
    uint2 st0; st0.x = w0; st0.y = w1;
    uint2 st1; st1.x = w2; st1.y = w3;
    *(uint2*)(out + qrow * D + h * DH + q4 * 4) = st0;
    *(uint2*)(out + qrow * D + h * DH + 16 + q4 * 4) = st1;
}

extern "C" void kernel_launch(void* const* d_in, const int* in_sizes, int n_in,
                              void* d_out, int out_size, void* d_ws, size_t ws_size,
                              hipStream_t stream) {
    const float* meas_xy = (const float*)d_in[0];
    const float* meas_v  = (const float*)d_in[1];
    const float* bs_xy   = (const float*)d_in[2];
    const int*   task_id = (const int*)d_in[3];
    const float* city    = (const float*)d_in[4];
    const float* mp_w1 = (const float*)d_in[5];  const float* mp_b1 = (const float*)d_in[6];
    const float* mp_w2 = (const float*)d_in[7];  const float* mp_b2 = (const float*)d_in[8];
    const float* bp_w1 = (const float*)d_in[9];  const float* bp_b1 = (const float*)d_in[10];
    const float* bp_w2 = (const float*)d_in[11]; const float* bp_b2 = (const float*)d_in[12];
    const float* env_w1 = (const float*)d_in[13]; const float* env_b1 = (const float*)d_in[14];
    const float* env_w2 = (const float*)d_in[15]; const float* env_b2 = (const float*)d_in[16];
    const float* env_w3 = (const float*)d_in[17]; const float* env_b3 = (const float*)d_in[18];
    const float* task_emb = (const float*)d_in[19];
    const float* tp_w = (const float*)d_in[20]; const float* tp_b = (const float*)d_in[21];
    const float* grid_pos = (const float*)d_in[22];
    const float* dens_w = (const float*)d_in[23]; const float* dens_b = (const float*)d_in[24];
    const float* ln1_w = (const float*)d_in[25]; const float* ln1_b = (const float*)d_in[26];
    const float* wq = (const float*)d_in[27]; const float* bq = (const float*)d_in[28];
    const float* wk = (const float*)d_in[29]; const float* bk = (const float*)d_in[30];
    const float* wv = (const float*)d_in[31]; const float* bv = (const float*)d_in[32];
    const float* wo = (const float*)d_in[33]; const float* bo = (const float*)d_in[34];
    const float* ln2_w = (const float*)d_in[35]; const float* ln2_b = (const float*)d_in[36];
    const float* ff_w1 = (const float*)d_in[37]; const float* ff_b1 = (const float*)d_in[38];
    const float* ff_w2 = (const float*)d_in[39]; const float* ff_b2 = (const float*)d_in[40];
    const float* tfp_w = (const float*)d_in[41]; const float* tfp_b = (const float*)d_in[42];
    const float* head_w = (const float*)d_in[43]; const float* head_b = (const float*)d_in[44];
    float* out = (float*)d_out;

    float* ws = (float*)d_ws;
    size_t off = 0;
    float* src_xy = ws + off; off += (size_t)B * NS * 2 + 128;
    float* dens   = ws + off; off += (size_t)B * KK;
    float* tvec   = ws + off; off += (size_t)B * D;
    float* h1     = ws + off; off += (size_t)B * EC * KK;
    float* grid   = ws + off; off += (size_t)B * KK * D;
    unsigned short* srcbf = (unsigned short*)(ws + off); off += (size_t)MSRCP * D / 2;
    unsigned short* khd   = (unsigned short*)(ws + off); off += (size_t)B * 8 * 544 * 32 / 2;
    unsigned short* vch   = (unsigned short*)(ws + off); off += (size_t)B * 8 * 17 * 1024 / 2;
    float* qreg   = ws + off; off += (size_t)B * KK * D / 2;   // qbf; hosts h2 f32 early
    unsigned short* qbf = (unsigned short*)qreg;
    float* h2     = qreg;
    unsigned short* xbf    = (unsigned short*)(ws + off); off += (size_t)B * KK * D / 2;
    unsigned short* attnbf = (unsigned short*)(ws + off); off += (size_t)B * KK * D / 2;
    unsigned short* ndbf   = (unsigned short*)(ws + off); off += (size_t)B * 64 * 34816 / 2;  // 17.8 MB
    unsigned short* hidbf  = (unsigned short*)(ws + off); off += (size_t)B * KK * DFF / 2;    // 32 MB
    unsigned short* wqT  = (unsigned short*)(ws + off); off += (size_t)LYR * D * D / 2;
    unsigned short* kvT  = (unsigned short*)(ws + off); off += (size_t)LYR * 512 * D / 2;
    unsigned short* woT  = (unsigned short*)(ws + off); off += (size_t)LYR * D * D / 2;
    unsigned short* ff1T = (unsigned short*)(ws + off); off += (size_t)LYR * D * DFF / 2;
    unsigned short* ff2T = (unsigned short*)(ws + off); off += (size_t)LYR * DFF * D / 2;
    unsigned short* tfpT = (unsigned short*)(ws + off); off += (size_t)T * D * D / 2;
    float* kvbias = ws + off; off += (size_t)LYR * 512;
    (void)ws_size; (void)n_in; (void)in_sizes; (void)out_size;

    const int M = B * KK;       // 16384

    pre1_k<<<6116, 256, 0, stream>>>(
        wq, wk, wv, wo, ff_w1, ff_w2, tfp_w, bk, bv,
        wqT, kvT, woT, ff1T, ff2T, tfpT, kvbias,
        meas_xy, meas_v, bs_xy, mp_w1, mp_b1, mp_w2, mp_b2,
        bp_w1, bp_b1, bp_w2, bp_b2, srcbf, src_xy,
        dens, city, env_w1, env_b1, h1,
        task_emb, task_id, tp_w, tp_b, tvec, khd, vch);
    conv2_k<<<512, 256, 0, stream>>>(h1, env_w2, env_b2, h2);
    pre2_k<<<2368, 256, 0, stream>>>(h2, env_w3, env_b3, grid_pos, tvec, grid,
                                     src_xy, ndbf, out, head_b);

    for (int l = 0; l < LYR; l++) {
        dens_ln_k<1><<<M / 4, 256, 0, stream>>>(grid, dens, dens_w + l * D, dens_b + l * D,
                                                ln1_w + l * D, ln1_b + l * D, xbf);
        qkv_k<<<dim3(12, 256), 256, 0, stream>>>(
            xbf, wqT + (size_t)l * D * D, bq + l * D, qbf,
            srcbf, kvT + (size_t)l * 512 * D, kvbias + l * 512, khd, vch);
        attn_mfma<<<B * NH * 64, 256, 0, stream>>>(qbf, khd, vch, ndbf, attnbf);
        gemm_k<0, 1, 0, 0, 0><<<dim3(4, 256), 256, 0, stream>>>(
            attnbf, woT + (size_t)l * D * D, bo + l * D, grid, M, D, D, nullptr, nullptr, nullptr);
        dens_ln_k<0><<<M / 4, 256, 0, stream>>>(grid, nullptr, nullptr, nullptr,
                                                ln2_w + l * D, ln2_b + l * D, xbf);
        gemm_k<1, 0, 1, 0, 0><<<dim3(16, 256), 256, 0, stream>>>(
            xbf, ff1T + (size_t)l * D * DFF, ff_b1 + l * DFF, hidbf, M, D, DFF,
            nullptr, nullptr, nullptr);
        if (l == 0) {
            gemm_k<0, 1, 0, 0, 0><<<dim3(4, 256), 256, 0, stream>>>(
                hidbf, ff2T + (size_t)l * DFF * D, ff_b2 + l * D, grid, M, DFF, D,
                nullptr, nullptr, nullptr);
        } else {
            gemm_k<0, 1, 0, 0, 1><<<dim3(4, 256), 256, 0, stream>>>(
                hidbf, ff2T + (size_t)l * DFF * D, ff_b2 + l * D, grid, M, DFF, D,
                nullptr, nullptr, xbf);
        }
    }
    gemm_k<1, 0, 0, 1, 0><<<dim3(4, 256), 256, 0, stream>>>(
        xbf, tfpT, tfp_b, out, M, D, D, task_id, head_w, nullptr);
}